// Round 8
// baseline (209.618 us; speedup 1.0000x reference)
//
#include <hip/hip_runtime.h>
#include <hip/hip_bf16.h>

#define SLOPE 0.1f

// ---- ws int-index layout: [0]=bf flag ----
// ---- ws float-index layout ----
#define OFF_QW    1816    // 32   q_weights (softmax), [30,32) zero
#define OFF_QNI   1846    // 32   1/||QE[q]||, [30,32) zero
#define OFF_QNS   1876    // 32   1/||QC[q]||, [30,32) zero
#define OFF_QNN   1906    // 32   ||QE[q]|| (one-hot threshold), [30,32) zero
#define OFF_B1    4606    // 30
#define OFF_B2    7336    // 30
#define OFF_LQ1W  7366    // 48
#define OFF_LQ1B  7414    // 8
#define OFF_LQ2W  7422    // 8
#define OFF_LQ2B  7430    // 1
#define OFF_SOW   7431    // 4
#define OFF_SOB   7435    // 1
#define OFF_FLW   7436    // 5
#define OFF_FLB   7441    // 1
// ---- bf16 (u16-index) region, starts at byte 32768 ----
#define U16_QEA   16384   // 32 rows x 32  (B-operand QE, zeros at d>=30, q>=30)
#define U16_QCA   17408   // 32 rows x 32  (B-operand QC)
#define U16_WB1   18432   // 32 rows x 96  (B-operand conv1 W[o][kk], kk=k*30+i)
#define U16_WB2   21504   // 32 rows x 96

typedef __attribute__((ext_vector_type(8))) __bf16 bf16x8;
typedef __attribute__((ext_vector_type(4))) float f32x4;

union Frag { uint4 u4; uint u[4]; bf16x8 v; };

__device__ __forceinline__ float bf2f(ushort h) {
    union { uint u; float f; } c; c.u = ((uint)h) << 16; return c.f;
}
__device__ __forceinline__ ushort f2bf(float f) {   // RNE, finite inputs
    union { float f; uint u; } c; c.f = f;
    uint u = c.u;
    return (ushort)((u + 0x7FFFu + ((u >> 16) & 1u)) >> 16);
}
__device__ __forceinline__ float ldx(const void* p, long i, int bf) {
    if (bf) return bf2f(((const ushort*)p)[i]);
    return ((const float*)p)[i];
}
#define CE(x, y) { float _hi = fmaxf(x, y), _lo = fminf(x, y); x = _hi; y = _lo; }

__device__ __forceinline__ void sort4d(float& a, float& b, float& c, float& d) {
    CE(a, b); CE(c, d); CE(a, c); CE(b, d); CE(b, c);
}
// merge two sorted-desc 4-lists -> top5 desc
__device__ __forceinline__ void merge44_5(const float* a, const float* b, float* t) {
    t[0] = fmaxf(a[0], b[0]);
    t[1] = fmaxf(fminf(a[0], b[0]), fmaxf(a[1], b[1]));
    t[2] = fmaxf(fmaxf(fminf(a[0], b[1]), fminf(a[1], b[0])), fmaxf(a[2], b[2]));
    t[3] = fmaxf(fmaxf(fminf(a[0], b[2]), fminf(a[1], b[1])),
                 fmaxf(fminf(a[2], b[0]), fmaxf(a[3], b[3])));
    t[4] = fmaxf(fmaxf(fminf(a[0], b[3]), fminf(a[1], b[2])),
                 fmaxf(fminf(a[2], b[1]), fminf(a[3], b[0])));
}
// merge sorted5 + sorted4 -> top5
__device__ __forceinline__ void merge54_5(const float* a, const float* b, float* t) {
    t[0] = fmaxf(a[0], b[0]);
    t[1] = fmaxf(fminf(a[0], b[0]), fmaxf(a[1], b[1]));
    t[2] = fmaxf(fmaxf(fminf(a[0], b[1]), fminf(a[1], b[0])), fmaxf(a[2], b[2]));
    t[3] = fmaxf(fmaxf(fminf(a[0], b[2]), fminf(a[1], b[1])),
                 fmaxf(fminf(a[2], b[0]), fmaxf(a[3], b[3])));
    t[4] = fmaxf(fmaxf(fmaxf(fminf(a[0], b[3]), fminf(a[1], b[2])),
                       fmaxf(fminf(a[2], b[1]), fminf(a[3], b[0]))), a[4]);
}
// merge two sorted5 -> top5
__device__ __forceinline__ void merge55_5(const float* a, const float* b, float* t) {
    t[0] = fmaxf(a[0], b[0]);
    t[1] = fmaxf(fminf(a[0], b[0]), fmaxf(a[1], b[1]));
    t[2] = fmaxf(fmaxf(fminf(a[0], b[1]), fminf(a[1], b[0])), fmaxf(a[2], b[2]));
    t[3] = fmaxf(fmaxf(fminf(a[0], b[2]), fminf(a[1], b[1])),
                 fmaxf(fminf(a[2], b[0]), fmaxf(a[3], b[3])));
    t[4] = fmaxf(fmaxf(fmaxf(fminf(a[0], b[3]), fminf(a[1], b[2])),
                       fmaxf(fminf(a[2], b[1]), fminf(a[3], b[0]))),
                 fmaxf(a[4], b[4]));
}

// dtype detection: f32 mantissa words carry wild bf16-exponent fields
__device__ __forceinline__ int detect_bf(const void* doc_in, int tid, int* scnt) {
    if (tid == 0) *scnt = 0;
    __syncthreads();
    const ushort* p = (const ushort*)doc_in;
    int local = 0;
    for (int i = tid; i < 4096; i += 256) {
        unsigned e = (p[i] >> 7) & 0xFFu;
        if (e != 0u && (e < 100u || e > 134u)) local++;
    }
    atomicAdd(scnt, local);
    __syncthreads();
    return (*scnt > 200) ? 0 : 1;
}

// ---------------- kernel 1 (3 blocks): detect + question path + repack ----------------
__global__ __launch_bounds__(256) void k_prep(
        const void* doc_in,
        const void* qe_in, const void* qidf_in,
        const void* w1_in, const void* b1_in,
        const void* w2_in, const void* b2_in,
        const void* qwW_in, const void* qwb_in,
        const void* lq1W_in, const void* lq1b_in,
        const void* lq2W_in, const void* lq2b_in,
        const void* soW_in, const void* sob_in,
        const void* flW_in, const void* flb_in,
        float* ws) {
    const int tid = threadIdx.x;
    const int blk = blockIdx.x;
    __shared__ float QE[900], T1[900], QC[900], W[2700], IDF[32], LG[32];
    __shared__ int scnt;

    const int bf = detect_bf(doc_in, tid, &scnt);
    ushort* wsu = (ushort*)ws;

    if (blk == 1) {
        if (tid == 0) { ((int*)ws)[0] = bf; }
        if (tid < 30) ws[OFF_B1 + tid] = ldx(b1_in, tid, bf);
        if (tid >= 30 && tid < 32) { ws[OFF_B1 + tid] = 0.f; ws[OFF_B2 + tid] = 0.f; }
        if (tid < 48) ws[OFF_LQ1W + tid] = ldx(lq1W_in, tid, bf);
        if (tid < 8)  { ws[OFF_LQ1B + tid] = ldx(lq1b_in, tid, bf);
                        ws[OFF_LQ2W + tid] = ldx(lq2W_in, tid, bf); }
        if (tid < 4)  ws[OFF_SOW + tid] = ldx(soW_in, tid, bf);
        if (tid < 5)  ws[OFF_FLW + tid] = ldx(flW_in, tid, bf);
        if (tid == 1) { ws[OFF_LQ2B] = ldx(lq2b_in, 0, bf);
                        ws[OFF_SOB]  = ldx(sob_in, 0, bf);
                        ws[OFF_FLB]  = ldx(flb_in, 0, bf); }
        for (int i = tid; i < 3072; i += 256) {
            int o = i / 96, kk = i % 96;
            float v1 = 0.f;
            if (o < 30 && kk < 90) {
                int ii = kk % 30, k = kk / 30;
                v1 = ldx(w1_in, (long)o*90 + ii*3 + k, bf);
            }
            wsu[U16_WB1 + i] = f2bf(v1);
        }
        return;
    }
    if (blk == 2) {
        if (tid < 30) ws[OFF_B2 + tid] = ldx(b2_in, tid, bf);
        for (int i = tid; i < 3072; i += 256) {
            int o = i / 96, kk = i % 96;
            float v2 = 0.f;
            if (o < 30 && kk < 90) {
                int ii = kk % 30, k = kk / 30;
                v2 = ldx(w2_in, (long)o*90 + ii*3 + k, bf);
            }
            wsu[U16_WB2 + i] = f2bf(v2);
        }
        return;
    }

    // ---- block 0: control word + question path ----
    if (tid == 0) { ((int*)ws)[0] = bf; }
    // zero-pad table tails so q in [30,32) is exactly dead in k_main
    if (tid >= 30 && tid < 32) {
        ws[OFF_QW + tid] = 0.f; ws[OFF_QNI + tid] = 0.f;
        ws[OFF_QNS + tid] = 0.f; ws[OFF_QNN + tid] = 0.f;
    }

    for (int i = tid; i < 900; i += 256) QE[i] = ldx(qe_in, i, bf);
    if (tid < 30) IDF[tid] = ldx(qidf_in, tid, bf);
    for (int i = tid; i < 2700; i += 256) W[i] = ldx(w1_in, i, bf);
    __syncthreads();

    for (int idx = tid; idx < 900; idx += 256) {
        int s = idx / 30, o = idx % 30;
        float acc = ldx(b1_in, o, bf);
        for (int k = 0; k < 3; ++k) {
            int t = s + k - 1;
            if (t < 0 || t >= 30) continue;
            for (int i = 0; i < 30; ++i) acc += QE[t*30 + i] * W[o*90 + i*3 + k];
        }
        acc = acc >= 0.f ? acc : SLOPE * acc;
        T1[idx] = acc + QE[idx];
    }
    __syncthreads();
    for (int i = tid; i < 2700; i += 256) W[i] = ldx(w2_in, i, bf);
    __syncthreads();
    for (int idx = tid; idx < 900; idx += 256) {
        int s = idx / 30, o = idx % 30;
        float acc = ldx(b2_in, o, bf);
        for (int k = 0; k < 3; ++k) {
            int t = s + k - 1;
            if (t < 0 || t >= 30) continue;
            for (int i = 0; i < 30; ++i) acc += T1[t*30 + i] * W[o*90 + i*3 + k];
        }
        acc = acc >= 0.f ? acc : SLOPE * acc;
        QC[idx] = acc + T1[idx];
    }
    __syncthreads();

    if (tid < 30) {
        float s1 = 0.f, s2 = 0.f;
        for (int d = 0; d < 30; ++d) {
            float a = QE[tid*30 + d]; s1 += a*a;
            float b = QC[tid*30 + d]; s2 += b*b;
        }
        float n1 = sqrtf(s1);
        ws[OFF_QNN + tid] = n1;
        ws[OFF_QNI + tid] = 1.0f / n1;
        ws[OFF_QNS + tid] = 1.0f / sqrtf(s2);
        float z = ldx(qwb_in, 0, bf);
        for (int d = 0; d < 30; ++d) z += QC[tid*30 + d] * ldx(qwW_in, d, bf);
        z += IDF[tid] * ldx(qwW_in, 30, bf);
        LG[tid] = z;
    }
    __syncthreads();
    if (tid == 0) {
        float m = -1e30f;
        for (int q = 0; q < 30; ++q) m = fmaxf(m, LG[q]);
        float sum = 0.f, e[30];
        for (int q = 0; q < 30; ++q) { e[q] = expf(LG[q] - m); sum += e[q]; }
        for (int q = 0; q < 30; ++q) ws[OFF_QW + q] = e[q] / sum;
    }
    for (int i = tid; i < 1024; i += 256) {
        int q = i >> 5, d = i & 31;
        float ve = (q < 30 && d < 30) ? QE[q*30 + d] : 0.f;
        float vc = (q < 30 && d < 30) ? QC[q*30 + d] : 0.f;
        wsu[U16_QEA + i] = f2bf(ve);
        wsu[U16_QCA + i] = f2bf(vc);
    }
}

// ---------------- kernel 2: barrier-free, one sentence per WAVE ----------------
// 128 threads = 2 waves = 2 sentences per block; grid 2000. Each wave owns
// private XA/XB/INVX LDS regions; all producer-consumer ordering is intra-wave
// (lgkmcnt), so there is NO __syncthreads in this kernel.
// LDS row layout: 16-dword zero header (row s=-1, 16B-aligned staging), row s
// at dword 16 + s*15, rows 100..101 zeroed. Total 1546 dwords per buffer.
__global__ __launch_bounds__(128, 3) void k_main(const void* doc_in, const void* gaf_in,
                                                 void* out, float* ws) {
    const int tid = threadIdx.x;
    const int wid = tid >> 6;              // wave = sentence slot
    const int lane = tid & 63;
    const int l15 = lane & 15;
    const int quad = lane >> 4;
    const int sent = blockIdx.x * 2 + wid;
    const int bf = ((const int*)ws)[0];

    __shared__ __align__(16) uint XAbuf[2][1546];
    __shared__ __align__(16) uint XBbuf[2][1546];
    __shared__ __align__(16) float INVXbuf[2][112];
    __shared__ float IQI[32], IQS[32], QNN[32], BI1[32], BI2[32], QWs[32];

    uint* XA = XAbuf[wid];
    uint* XB = XBbuf[wid];
    float* IX = INVXbuf[wid];
    ushort* XAu = (ushort*)XA;

    const ushort* wsu = (const ushort*)ws;
    const uint4* qeA = (const uint4*)(wsu + U16_QEA);
    const uint4* qcA = (const uint4*)(wsu + U16_QCA);
    const uint4* wb1 = (const uint4*)(wsu + U16_WB1);
    const uint4* wb2 = (const uint4*)(wsu + U16_WB2);

    // gaf prefetch (used at the very end)
    float ga0 = ldx(gaf_in, (long)sent*3 + 0, bf);
    float ga1 = ldx(gaf_in, (long)sent*3 + 1, bf);
    float ga2 = ldx(gaf_in, (long)sent*3 + 2, bf);

    // small tables: both waves write identical values (benign duplicate)
    if (lane < 32) {
        IQI[lane] = ws[OFF_QNI + lane];
        IQS[lane] = ws[OFF_QNS + lane];
        QNN[lane] = ws[OFF_QNN + lane];
        BI1[lane] = ws[OFF_B1 + lane];
        BI2[lane] = ws[OFF_B2 + lane];
        QWs[lane] = ws[OFF_QW + lane];
    }

    // ---- stage: zero pads + sentence load ----
    if (lane < 46) {
        int j = (lane < 16) ? lane : (1500 + lane);   // [0,16) and [1516,1546)
        XA[j] = 0u; XB[j] = 0u;
    }
    if (bf) {
        const uint4* g = (const uint4*)((const ushort*)doc_in + (size_t)sent * 3000);
        uint4* dst = (uint4*)(XA + 16);               // 64B-aligned
        for (int i = lane; i < 375; i += 64) dst[i] = g[i];
    } else {
        const float* p = (const float*)doc_in + (size_t)sent * 3000;
        for (int i = lane; i < 3000; i += 64) XAu[32 + i] = f2bf(p[i]);
    }

    // ---- inverse row norms (rows of XA) ----
    auto norms = [&](const uint* src) {
        #pragma unroll
        for (int pass = 0; pass < 2; ++pass) {
            int s = lane + pass * 64;
            if (s < 100) {
                const uint* r = src + 16 + s * 15;
                float sum = 0.f;
                #pragma unroll
                for (int i = 0; i < 15; ++i) {
                    uint u = r[i];
                    float lo = __uint_as_float(u << 16);
                    float hi = __uint_as_float(u & 0xFFFF0000u);
                    sum += lo * lo + hi * hi;
                }
                IX[s] = 1.f / sqrtf(sum);
            }
        }
        if (lane >= 36 && lane < 48) IX[lane + 64] = 0.f;   // [100,112) zero
    };
    norms(XA);

    // ---- transposed sim + in-lane pool, both q-tiles in one wave ----
    // fe[t][0..5] per lane: q = t*16 + l15 (post-butterfly, all quads identical)
    float fe[2][6];
    auto sim_pool = [&](const uint4* qa, const float* IQ, int fbase, bool do_oh) {
        Frag b0, b1;
        b0.u4 = qa[l15 * 4 + quad];
        b1.u4 = qa[(16 + l15) * 4 + quad];
        f32x4 acc0[7], acc1[7];
        #pragma unroll
        for (int mt = 0; mt < 7; ++mt) {
            int m = mt * 16 + l15;                     // s-row of A
            Frag a;
            if (m < 100) {
                int base = 16 + m * 15 + quad * 4;
                a.u[0] = XA[base];     a.u[1] = XA[base + 1];
                a.u[2] = XA[base + 2]; a.u[3] = XA[base + 3];
            } else { a.u[0] = a.u[1] = a.u[2] = a.u[3] = 0u; }
            f32x4 z = {0.f, 0.f, 0.f, 0.f};
            acc0[mt] = __builtin_amdgcn_mfma_f32_16x16x32_bf16(a.v, b0.v, z, 0, 0, 0);
            acc1[mt] = __builtin_amdgcn_mfma_f32_16x16x32_bf16(a.v, b1.v, z, 0, 0, 0);
        }
        float ixa[7][4];
        const float4* IX4 = (const float4*)IX;
        #pragma unroll
        for (int mt = 0; mt < 7; ++mt) {
            float4 v4 = IX4[mt * 4 + quad];
            ixa[mt][0] = v4.x; ixa[mt][1] = v4.y; ixa[mt][2] = v4.z; ixa[mt][3] = v4.w;
        }
        #pragma unroll
        for (int t = 0; t < 2; ++t) {
            const f32x4* acc = t ? acc1 : acc0;
            int q = t * 16 + l15;
            float thr = 0.999f * QNN[q];
            float iq  = IQ[q];
            float g[7][4];
            int cnt = 0;
            #pragma unroll
            for (int mt = 0; mt < 7; ++mt) {
                #pragma unroll
                for (int r = 0; r < 4; ++r) {
                    float u = acc[mt][r] * ixa[mt][r];
                    if (mt == 6 && (quad * 4 + r) >= 4) u = -1e30f;   // s >= 100
                    g[mt][r] = u;
                    if (do_oh) cnt += (u > thr) ? 1 : 0;
                }
            }
            #pragma unroll
            for (int mt = 0; mt < 7; ++mt) sort4d(g[mt][0], g[mt][1], g[mt][2], g[mt][3]);
            float p0[5], p1[5], p2[5], q0[5], q1[5], tt[5];
            merge44_5(g[0], g[1], p0);
            merge44_5(g[2], g[3], p1);
            merge44_5(g[4], g[5], p2);
            merge55_5(p0, p1, q0);
            merge54_5(p2, g[6], q1);
            merge55_5(q0, q1, tt);
            #pragma unroll
            for (int d = 16; d < 64; d <<= 1) {        // butterfly across quads
                float pp[5];
                pp[0] = __shfl_xor(tt[0], d); pp[1] = __shfl_xor(tt[1], d);
                pp[2] = __shfl_xor(tt[2], d); pp[3] = __shfl_xor(tt[3], d);
                pp[4] = __shfl_xor(tt[4], d);
                if (do_oh) cnt += __shfl_xor(cnt, d);
                float tn[5];
                merge55_5(tt, pp, tn);
                tt[0] = tn[0]; tt[1] = tn[1]; tt[2] = tn[2]; tt[3] = tn[3]; tt[4] = tn[4];
            }
            if (do_oh) {
                fe[t][0] = cnt > 0 ? 1.f : 0.f;
                fe[t][1] = (float)(cnt > 5 ? 5 : cnt) * 0.2f;
            }
            fe[t][fbase]     = tt[0] * iq;
            fe[t][fbase + 1] = (tt[0] + tt[1] + tt[2] + tt[3] + tt[4]) * 0.2f * iq;
        }
    };

    // ---- conv (full, one wave): src -> dst, all 7 mt x 2 nt ----
    auto conv = [&](const uint* src, uint* dst, const uint4* wb, const float* bias) {
        const ushort* srcU = (const ushort*)src;
        ushort* dstU = (ushort*)dst;
        #pragma unroll
        for (int mt = 0; mt < 7; ++mt) {
            int sa = mt * 16 + l15;
            Frag a[3];
            #pragma unroll
            for (int k = 0; k < 3; ++k) {
                if (sa < 100) {
                    int base = 16 + (sa - 1) * 15 + k * 16 + quad * 4;
                    a[k].u[0] = src[base];     a[k].u[1] = src[base + 1];
                    a[k].u[2] = src[base + 2]; a[k].u[3] = src[base + 3];
                } else { a[k].u[0] = a[k].u[1] = a[k].u[2] = a[k].u[3] = 0u; }
            }
            #pragma unroll
            for (int nt = 0; nt < 2; ++nt) {
                f32x4 acc = {0.f, 0.f, 0.f, 0.f};
                #pragma unroll
                for (int k = 0; k < 3; ++k) {
                    Frag b;
                    b.u4 = wb[(nt * 16 + l15) * 12 + k * 4 + quad];
                    acc = __builtin_amdgcn_mfma_f32_16x16x32_bf16(a[k].v, b.v, acc, 0, 0, 0);
                }
                int o = nt * 16 + l15;
                if (o < 30) {
                    float bo = bias[o];
                    #pragma unroll
                    for (int r = 0; r < 4; ++r) {
                        int s = mt * 16 + quad * 4 + r;
                        if (s < 100) {
                            float v = acc[r] + bo;
                            v = fmaxf(v, SLOPE * v);               // leaky (SLOPE>0)
                            v += bf2f(srcU[32 + s * 30 + o]);      // residual
                            dstU[32 + s * 30 + o] = f2bf(v);
                        }
                    }
                }
            }
        }
    };

    sim_pool(qeA, IQI, 2, true);       // sim_insens + one-hot (reads XA)
    conv(XA, XB, wb1, BI1);            // conv1
    conv(XB, XA, wb2, BI2);            // conv2 (XA := conv_res)
    norms(XA);                         // inverse norms of conv_res
    sim_pool(qcA, IQS, 4, false);      // sim_sens

    // ---- per-q MLP (redundant per lane; all quads hold identical fe) ----
    auto mlp = [&](const float* f) {
        float lo = ws[OFF_LQ2B];
        #pragma unroll
        for (int j = 0; j < 8; ++j) {
            float h = ws[OFF_LQ1B + j];
            #pragma unroll
            for (int c = 0; c < 6; ++c) h += f[c] * ws[OFF_LQ1W + j*6 + c];
            h = fmaxf(h, SLOPE * h);
            lo += h * ws[OFF_LQ2W + j];
        }
        return lo;
    };
    float val = mlp(fe[0]) * QWs[l15] + mlp(fe[1]) * QWs[16 + l15];  // QWs[q>=30]=0
    #pragma unroll
    for (int d = 1; d < 16; d <<= 1) val += __shfl_xor(val, d);      // sum over l15
    if (lane == 0) {
        float emit = val * (1.f / 30.f);
        float z = ws[OFF_SOB];
        z += ga0 * ws[OFF_SOW + 0];
        z += ga1 * ws[OFF_SOW + 1];
        z += ga2 * ws[OFF_SOW + 2];
        z += emit * ws[OFF_SOW + 3];
        float sc = 1.f / (1.f + expf(-z));
        if (bf) ((__hip_bfloat16*)out)[1 + sent] = __float2bfloat16(sc);
        else    ((float*)out)[1 + sent] = sc;
    }
}

// ---------------- kernel 3: doc-level head ----------------
__global__ __launch_bounds__(256) void k_final(const void* docgaf_in, void* out, const float* ws) {
    const int tid = threadIdx.x;
    const int bf = ((const int*)ws)[0];
    __shared__ float red[256];
    float m = -1e30f;
    for (int i = tid; i < 4000; i += 256) {
        float v = bf ? __bfloat162float(((const __hip_bfloat16*)out)[1 + i])
                     : ((const float*)out)[1 + i];
        m = fmaxf(m, v);
    }
    red[tid] = m;
    __syncthreads();
    for (int off = 128; off > 0; off >>= 1) {
        if (tid < off) red[tid] = fmaxf(red[tid], red[tid + off]);
        __syncthreads();
    }
    if (tid == 0) {
        float f = ws[OFF_FLB] + red[0] * ws[OFF_FLW + 0];
        for (int i = 0; i < 4; ++i) f += ldx(docgaf_in, i, bf) * ws[OFF_FLW + 1 + i];
        if (bf) ((__hip_bfloat16*)out)[0] = __float2bfloat16(f);
        else    ((float*)out)[0] = f;
    }
}

extern "C" void kernel_launch(void* const* d_in, const int* in_sizes, int n_in,
                              void* d_out, int out_size, void* d_ws, size_t ws_size,
                              hipStream_t stream) {
    float* ws = (float*)d_ws;
    k_prep<<<3, 256, 0, stream>>>(d_in[0], d_in[2], d_in[3], d_in[5], d_in[6], d_in[7], d_in[8],
                                  d_in[9], d_in[10], d_in[11], d_in[12], d_in[13], d_in[14],
                                  d_in[15], d_in[16], d_in[17], d_in[18], ws);
    k_main<<<2000, 128, 0, stream>>>(d_in[0], d_in[1], d_out, ws);
    k_final<<<1, 256, 0, stream>>>(d_in[4], d_out, ws);
}

// Round 9
// 191.726 us; speedup vs baseline: 1.0933x; 1.0933x over previous
//
#include <hip/hip_runtime.h>
#include <hip/hip_bf16.h>

#define SLOPE 0.1f

// ---- ws int-index layout: [0]=bf flag ----
// ---- ws float-index layout ----
#define OFF_QW    1816    // 30   q_weights (softmax)
#define OFF_QNI   1846    // 30   1/||QE[q]||
#define OFF_QNS   1876    // 30   1/||QC[q]||
#define OFF_QNN   1906    // 30   ||QE[q]|| (one-hot threshold)
#define OFF_B1    4606    // 30
#define OFF_B2    7336    // 30
#define OFF_LQ1W  7366    // 48
#define OFF_LQ1B  7414    // 8
#define OFF_LQ2W  7422    // 8
#define OFF_LQ2B  7430    // 1
#define OFF_SOW   7431    // 4
#define OFF_SOB   7435    // 1
#define OFF_FLW   7436    // 5
#define OFF_FLB   7441    // 1
// ---- bf16 (u16-index) region, starts at byte 32768 ----
#define U16_QEA   16384   // 32 rows x 32  (B-operand QE, zeros at d>=30, q>=30)
#define U16_QCA   17408   // 32 rows x 32  (B-operand QC)
#define U16_WB1   18432   // 32 rows x 96  (B-operand conv1 W[o][kk], kk=k*30+i)
#define U16_WB2   21504   // 32 rows x 96

typedef __attribute__((ext_vector_type(8))) __bf16 bf16x8;
typedef __attribute__((ext_vector_type(4))) float f32x4;

union Frag { uint4 u4; uint u[4]; bf16x8 v; };

__device__ __forceinline__ float bf2f(ushort h) {
    union { uint u; float f; } c; c.u = ((uint)h) << 16; return c.f;
}
__device__ __forceinline__ ushort f2bf(float f) {   // RNE, finite inputs
    union { float f; uint u; } c; c.f = f;
    uint u = c.u;
    return (ushort)((u + 0x7FFFu + ((u >> 16) & 1u)) >> 16);
}
__device__ __forceinline__ float ldx(const void* p, long i, int bf) {
    if (bf) return bf2f(((const ushort*)p)[i]);
    return ((const float*)p)[i];
}
#define CE(x, y) { float _hi = fmaxf(x, y), _lo = fminf(x, y); x = _hi; y = _lo; }

__device__ __forceinline__ void sort4d(float& a, float& b, float& c, float& d) {
    CE(a, b); CE(c, d); CE(a, c); CE(b, d); CE(b, c);
}
// merge two sorted-desc 4-lists -> top5 desc
__device__ __forceinline__ void merge44_5(const float* a, const float* b, float* t) {
    t[0] = fmaxf(a[0], b[0]);
    t[1] = fmaxf(fminf(a[0], b[0]), fmaxf(a[1], b[1]));
    t[2] = fmaxf(fmaxf(fminf(a[0], b[1]), fminf(a[1], b[0])), fmaxf(a[2], b[2]));
    t[3] = fmaxf(fmaxf(fminf(a[0], b[2]), fminf(a[1], b[1])),
                 fmaxf(fminf(a[2], b[0]), fmaxf(a[3], b[3])));
    t[4] = fmaxf(fmaxf(fminf(a[0], b[3]), fminf(a[1], b[2])),
                 fmaxf(fminf(a[2], b[1]), fminf(a[3], b[0])));
}
// merge sorted5 + sorted4 -> top5
__device__ __forceinline__ void merge54_5(const float* a, const float* b, float* t) {
    t[0] = fmaxf(a[0], b[0]);
    t[1] = fmaxf(fminf(a[0], b[0]), fmaxf(a[1], b[1]));
    t[2] = fmaxf(fmaxf(fminf(a[0], b[1]), fminf(a[1], b[0])), fmaxf(a[2], b[2]));
    t[3] = fmaxf(fmaxf(fminf(a[0], b[2]), fminf(a[1], b[1])),
                 fmaxf(fminf(a[2], b[0]), fmaxf(a[3], b[3])));
    t[4] = fmaxf(fmaxf(fmaxf(fminf(a[0], b[3]), fminf(a[1], b[2])),
                       fmaxf(fminf(a[2], b[1]), fminf(a[3], b[0]))), a[4]);
}
// merge two sorted5 -> top5
__device__ __forceinline__ void merge55_5(const float* a, const float* b, float* t) {
    t[0] = fmaxf(a[0], b[0]);
    t[1] = fmaxf(fminf(a[0], b[0]), fmaxf(a[1], b[1]));
    t[2] = fmaxf(fmaxf(fminf(a[0], b[1]), fminf(a[1], b[0])), fmaxf(a[2], b[2]));
    t[3] = fmaxf(fmaxf(fminf(a[0], b[2]), fminf(a[1], b[1])),
                 fmaxf(fminf(a[2], b[0]), fmaxf(a[3], b[3])));
    t[4] = fmaxf(fmaxf(fmaxf(fminf(a[0], b[3]), fminf(a[1], b[2])),
                       fmaxf(fminf(a[2], b[1]), fminf(a[3], b[0]))),
                 fmaxf(a[4], b[4]));
}

// dtype detection: f32 mantissa words carry wild bf16-exponent fields
__device__ __forceinline__ int detect_bf(const void* doc_in, int tid, int* scnt) {
    if (tid == 0) *scnt = 0;
    __syncthreads();
    const ushort* p = (const ushort*)doc_in;
    int local = 0;
    for (int i = tid; i < 4096; i += 256) {
        unsigned e = (p[i] >> 7) & 0xFFu;
        if (e != 0u && (e < 100u || e > 134u)) local++;
    }
    atomicAdd(scnt, local);
    __syncthreads();
    return (*scnt > 200) ? 0 : 1;
}

// ---------------- kernel 1 (3 blocks): detect + question path + repack ----------------
__global__ __launch_bounds__(256) void k_prep(
        const void* doc_in,
        const void* qe_in, const void* qidf_in,
        const void* w1_in, const void* b1_in,
        const void* w2_in, const void* b2_in,
        const void* qwW_in, const void* qwb_in,
        const void* lq1W_in, const void* lq1b_in,
        const void* lq2W_in, const void* lq2b_in,
        const void* soW_in, const void* sob_in,
        const void* flW_in, const void* flb_in,
        float* ws) {
    const int tid = threadIdx.x;
    const int blk = blockIdx.x;
    __shared__ float QE[900], T1[900], QC[900], W[2700], IDF[32], LG[32];
    __shared__ int scnt;

    const int bf = detect_bf(doc_in, tid, &scnt);
    ushort* wsu = (ushort*)ws;

    if (blk == 1) {
        if (tid == 0) { ((int*)ws)[0] = bf; }
        if (tid < 30) ws[OFF_B1 + tid] = ldx(b1_in, tid, bf);
        if (tid < 48) ws[OFF_LQ1W + tid] = ldx(lq1W_in, tid, bf);
        if (tid < 8)  { ws[OFF_LQ1B + tid] = ldx(lq1b_in, tid, bf);
                        ws[OFF_LQ2W + tid] = ldx(lq2W_in, tid, bf); }
        if (tid < 4)  ws[OFF_SOW + tid] = ldx(soW_in, tid, bf);
        if (tid < 5)  ws[OFF_FLW + tid] = ldx(flW_in, tid, bf);
        if (tid == 1) { ws[OFF_LQ2B] = ldx(lq2b_in, 0, bf);
                        ws[OFF_SOB]  = ldx(sob_in, 0, bf);
                        ws[OFF_FLB]  = ldx(flb_in, 0, bf); }
        for (int i = tid; i < 3072; i += 256) {
            int o = i / 96, kk = i % 96;
            float v1 = 0.f;
            if (o < 30 && kk < 90) {
                int ii = kk % 30, k = kk / 30;
                v1 = ldx(w1_in, (long)o*90 + ii*3 + k, bf);
            }
            wsu[U16_WB1 + i] = f2bf(v1);
        }
        return;
    }
    if (blk == 2) {
        if (tid < 30) ws[OFF_B2 + tid] = ldx(b2_in, tid, bf);
        for (int i = tid; i < 3072; i += 256) {
            int o = i / 96, kk = i % 96;
            float v2 = 0.f;
            if (o < 30 && kk < 90) {
                int ii = kk % 30, k = kk / 30;
                v2 = ldx(w2_in, (long)o*90 + ii*3 + k, bf);
            }
            wsu[U16_WB2 + i] = f2bf(v2);
        }
        return;
    }

    // ---- block 0: control word + question path ----
    if (tid == 0) { ((int*)ws)[0] = bf; }

    for (int i = tid; i < 900; i += 256) QE[i] = ldx(qe_in, i, bf);
    if (tid < 30) IDF[tid] = ldx(qidf_in, tid, bf);
    for (int i = tid; i < 2700; i += 256) W[i] = ldx(w1_in, i, bf);
    __syncthreads();

    for (int idx = tid; idx < 900; idx += 256) {
        int s = idx / 30, o = idx % 30;
        float acc = ldx(b1_in, o, bf);
        for (int k = 0; k < 3; ++k) {
            int t = s + k - 1;
            if (t < 0 || t >= 30) continue;
            for (int i = 0; i < 30; ++i) acc += QE[t*30 + i] * W[o*90 + i*3 + k];
        }
        acc = acc >= 0.f ? acc : SLOPE * acc;
        T1[idx] = acc + QE[idx];
    }
    __syncthreads();
    for (int i = tid; i < 2700; i += 256) W[i] = ldx(w2_in, i, bf);
    __syncthreads();
    for (int idx = tid; idx < 900; idx += 256) {
        int s = idx / 30, o = idx % 30;
        float acc = ldx(b2_in, o, bf);
        for (int k = 0; k < 3; ++k) {
            int t = s + k - 1;
            if (t < 0 || t >= 30) continue;
            for (int i = 0; i < 30; ++i) acc += T1[t*30 + i] * W[o*90 + i*3 + k];
        }
        acc = acc >= 0.f ? acc : SLOPE * acc;
        QC[idx] = acc + T1[idx];
    }
    __syncthreads();

    if (tid < 30) {
        float s1 = 0.f, s2 = 0.f;
        for (int d = 0; d < 30; ++d) {
            float a = QE[tid*30 + d]; s1 += a*a;
            float b = QC[tid*30 + d]; s2 += b*b;
        }
        float n1 = sqrtf(s1);
        ws[OFF_QNN + tid] = n1;
        ws[OFF_QNI + tid] = 1.0f / n1;
        ws[OFF_QNS + tid] = 1.0f / sqrtf(s2);
        float z = ldx(qwb_in, 0, bf);
        for (int d = 0; d < 30; ++d) z += QC[tid*30 + d] * ldx(qwW_in, d, bf);
        z += IDF[tid] * ldx(qwW_in, 30, bf);
        LG[tid] = z;
    }
    __syncthreads();
    if (tid == 0) {
        float m = -1e30f;
        for (int q = 0; q < 30; ++q) m = fmaxf(m, LG[q]);
        float sum = 0.f, e[30];
        for (int q = 0; q < 30; ++q) { e[q] = expf(LG[q] - m); sum += e[q]; }
        for (int q = 0; q < 30; ++q) ws[OFF_QW + q] = e[q] / sum;
    }
    for (int i = tid; i < 1024; i += 256) {
        int q = i >> 5, d = i & 31;
        float ve = (q < 30 && d < 30) ? QE[q*30 + d] : 0.f;
        float vc = (q < 30 && d < 30) ? QC[q*30 + d] : 0.f;
        wsu[U16_QEA + i] = f2bf(ve);
        wsu[U16_QCA + i] = f2bf(vc);
    }
}

// ---------------- kernel 2: per-sentence fused MFMA pipeline ----------------
// R7 structure (2 cooperating waves per sentence, 44 VGPR) + norms fused into
// sim_pool via MFMA self-product (A-frag doubles as B-operand for X·X^T; the
// Gram diagonal is the squared row norm). 4 barriers instead of 6; the two
// 100-thread norm phases are gone.
__global__ __launch_bounds__(128, 4) void k_main(const void* doc_in, const void* gaf_in,
                                                 void* out, float* ws) {
    const int n = blockIdx.x;
    const int tid = threadIdx.x;
    const int bf = ((const int*)ws)[0];
    const int lane = tid & 63;
    const int wid = tid >> 6;          // 0 or 1
    const int l15 = lane & 15;
    const int quad = lane >> 4;

    __shared__ uint XA32[1546];        // X flat bf16: 103 rows x 30 (rows 0,101,102 zero)
    __shared__ uint XB32[1546];        // conv1 output, same layout
    __shared__ __align__(16) float INVX[112];   // all 112 written by sim_pool norm MFMA
    __shared__ float FE[30][6];
    __shared__ float IQI[32], IQS[32], QNN[32], BI1[32], BI2[32];

    ushort* XAu = (ushort*)XA32;
    const ushort* wsu = (const ushort*)ws;
    const uint4* qeA = (const uint4*)(wsu + U16_QEA);
    const uint4* qcA = (const uint4*)(wsu + U16_QCA);
    const uint4* wb1 = (const uint4*)(wsu + U16_WB1);
    const uint4* wb2 = (const uint4*)(wsu + U16_WB2);

    // prefetch gaf scalars (consumed at the very end by wave0 lane0)
    float ga0 = ldx(gaf_in, (long)n*3 + 0, bf);
    float ga1 = ldx(gaf_in, (long)n*3 + 1, bf);
    float ga2 = ldx(gaf_in, (long)n*3 + 2, bf);

    // ---- B0: zero pads, load sentence, cache small params in LDS ----
    for (int i = tid; i < 46; i += 128) {
        int j = (i < 15) ? i : (1500 + i);   // [0,15) and [1515,1546)
        XA32[j] = 0u; XB32[j] = 0u;
    }
    if (bf) {
        const uint* g = (const uint*)((const ushort*)doc_in + (size_t)n * 3000);
        for (int i = tid; i < 1500; i += 128) XA32[15 + i] = g[i];
    } else {
        const float* p = (const float*)doc_in + (size_t)n * 3000;
        for (int i = tid; i < 3000; i += 128) XAu[30 + i] = f2bf(p[i]);
    }
    if (tid < 32) {
        IQI[tid] = ws[OFF_QNI + tid];
        IQS[tid] = ws[OFF_QNS + tid];
        QNN[tid] = ws[OFF_QNN + tid];
        BI1[tid] = ws[OFF_B1 + tid];
        BI2[tid] = ws[OFF_B2 + tid];
    }
    __syncthreads();

    // transposed sim + MFMA-fused norms + in-lane pool; lane owns q = wid*16+l15.
    // Both waves redundantly compute all INVX entries (identical bits; benign race).
    auto sim_pool = [&](const uint4* qa, const float* IQ, int fbase, bool do_oh) {
        const int q = wid * 16 + l15;
        Frag b;
        b.u4 = qa[q * 4 + quad];            // B[k=quad*8+j][n=q] == Q[q][k] table row
        f32x4 acc[7];
        #pragma unroll
        for (int mt = 0; mt < 7; ++mt) {
            int m = mt * 16 + l15;          // s-row of A
            Frag a;
            if (m < 100) {
                int base = (m + 1) * 15 + quad * 4;
                a.u[0] = XA32[base];     a.u[1] = XA32[base + 1];
                a.u[2] = XA32[base + 2]; a.u[3] = XA32[base + 3];
            } else { a.u[0] = a.u[1] = a.u[2] = a.u[3] = 0u; }
            f32x4 z = {0.f, 0.f, 0.f, 0.f};
            acc[mt] = __builtin_amdgcn_mfma_f32_16x16x32_bf16(a.v, b.v, z, 0, 0, 0);
            // norms: a doubles as B-operand (A[m=l15][k] == B[k][n=l15] content);
            // Gram diag C[i][i] = ||X[mt*16+i]||^2 lives in lanes l15 == quad*4+r.
            f32x4 nrm = __builtin_amdgcn_mfma_f32_16x16x32_bf16(a.v, a.v, z, 0, 0, 0);
            #pragma unroll
            for (int r = 0; r < 4; ++r)
                if (l15 == quad * 4 + r) INVX[mt * 16 + l15] = 1.f / sqrtf(nrm[r]);
        }
        // u[s] = num * invx[s]; s = mt*16 + quad*4 + r (in-lane)
        const float4* INVX4 = (const float4*)INVX;
        float thr = 0.999f * QNN[q];        // u > thr  <=>  sim > 0.999
        float iq  = (q < 30) ? IQ[q] : 0.f;
        float g[7][4];
        int cnt = 0;
        #pragma unroll
        for (int mt = 0; mt < 7; ++mt) {
            float4 ix = INVX4[mt * 4 + quad];
            float ixa[4] = {ix.x, ix.y, ix.z, ix.w};
            #pragma unroll
            for (int r = 0; r < 4; ++r) {
                float u = acc[mt][r] * ixa[r];
                if (mt == 6 && (quad * 4 + r) >= 4) u = -1e30f;   // s >= 100 (kills 0*inf NaN)
                g[mt][r] = u;
                if (do_oh) cnt += (u > thr) ? 1 : 0;
            }
        }
        // in-lane top5-of-28: 7x sort4 + capped merge tree
        #pragma unroll
        for (int mt = 0; mt < 7; ++mt) sort4d(g[mt][0], g[mt][1], g[mt][2], g[mt][3]);
        float p0[5], p1[5], p2[5], q0[5], q1[5], t[5];
        merge44_5(g[0], g[1], p0);
        merge44_5(g[2], g[3], p1);
        merge44_5(g[4], g[5], p2);
        merge55_5(p0, p1, q0);
        merge54_5(p2, g[6], q1);
        merge55_5(q0, q1, t);
        // butterfly across the 4 quads (lanes xor 16, 32; l15 preserved)
        #pragma unroll
        for (int d = 16; d < 64; d <<= 1) {
            float pp[5];
            pp[0] = __shfl_xor(t[0], d); pp[1] = __shfl_xor(t[1], d);
            pp[2] = __shfl_xor(t[2], d); pp[3] = __shfl_xor(t[3], d);
            pp[4] = __shfl_xor(t[4], d);
            if (do_oh) cnt += __shfl_xor(cnt, d);
            float tn[5];
            merge55_5(t, pp, tn);
            t[0] = tn[0]; t[1] = tn[1]; t[2] = tn[2]; t[3] = tn[3]; t[4] = tn[4];
        }
        if (quad == 0 && q < 30) {
            if (do_oh) {
                FE[q][0] = cnt > 0 ? 1.f : 0.f;
                FE[q][1] = (float)(cnt > 5 ? 5 : cnt) * 0.2f;
            }
            FE[q][fbase]     = t[0] * iq;
            FE[q][fbase + 1] = (t[0] + t[1] + t[2] + t[3] + t[4]) * 0.2f * iq;
        }
    };

    // conv for one mt; A-fragments shared across nt tiles [nt0, nt1]
    auto conv_mt = [&](const uint* src32, uint* dst32, const uint4* wb,
                       const float* bias, int mt, int nt0, int nt1) {
        const ushort* srcU = (const ushort*)src32;
        ushort* dstU = (ushort*)dst32;
        int sa = mt * 16 + l15;
        Frag a[3];
        #pragma unroll
        for (int k = 0; k < 3; ++k) {
            if (sa < 100) {
                int base = sa * 15 + k * 16 + quad * 4;
                a[k].u[0] = src32[base];     a[k].u[1] = src32[base + 1];
                a[k].u[2] = src32[base + 2]; a[k].u[3] = src32[base + 3];
            } else { a[k].u[0] = a[k].u[1] = a[k].u[2] = a[k].u[3] = 0u; }
        }
        for (int nt = nt0; nt <= nt1; ++nt) {
            f32x4 acc = {0.f, 0.f, 0.f, 0.f};
            #pragma unroll
            for (int k = 0; k < 3; ++k) {
                Frag b;
                b.u4 = wb[(nt * 16 + l15) * 12 + k * 4 + quad];
                acc = __builtin_amdgcn_mfma_f32_16x16x32_bf16(a[k].v, b.v, acc, 0, 0, 0);
            }
            int o = nt * 16 + l15;
            if (o < 30) {
                float bo = bias[o];
                #pragma unroll
                for (int r = 0; r < 4; ++r) {
                    int s = mt * 16 + quad * 4 + r;
                    if (s < 100) {
                        float v = acc[r] + bo;
                        v = v >= 0.f ? v : SLOPE * v;
                        v += bf2f(srcU[(s + 1) * 30 + o]);
                        dstU[(s + 1) * 30 + o] = f2bf(v);
                    }
                }
            }
        }
    };

    // ---- B1: sim_insens (+norms) then conv1 XA->XB ----
    sim_pool(qeA, IQI, 2, true);
    conv_mt(XA32, XB32, wb1, BI1, wid,     0, 1);
    conv_mt(XA32, XB32, wb1, BI1, wid + 2, 0, 1);
    conv_mt(XA32, XB32, wb1, BI1, wid + 4, 0, 1);
    conv_mt(XA32, XB32, wb1, BI1, 6,       wid, wid);
    __syncthreads();

    // ---- B2: conv2 XB->XA ----
    conv_mt(XB32, XA32, wb2, BI2, wid,     0, 1);
    conv_mt(XB32, XA32, wb2, BI2, wid + 2, 0, 1);
    conv_mt(XB32, XA32, wb2, BI2, 6,       wid, wid);
    conv_mt(XB32, XA32, wb2, BI2, wid + 4, 0, 1);
    __syncthreads();

    // ---- B3: sim_sens (+norms of conv_res) ----
    sim_pool(qcA, IQS, 4, false);
    __syncthreads();

    // ---- B4: wave0: per-q MLP, butterfly-sum, score write ----
    if (wid == 0) {
        float val = 0.f;
        if (lane < 30) {
            float lo = ws[OFF_LQ2B];
            #pragma unroll
            for (int j = 0; j < 8; ++j) {
                float h = ws[OFF_LQ1B + j];
                #pragma unroll
                for (int f = 0; f < 6; ++f) h += FE[lane][f] * ws[OFF_LQ1W + j*6 + f];
                h = h >= 0.f ? h : SLOPE * h;
                lo += h * ws[OFF_LQ2W + j];
            }
            val = lo * ws[OFF_QW + lane];
        }
        for (int d = 32; d >= 1; d >>= 1) val += __shfl_xor(val, d);
        if (lane == 0) {
            float emit = val * (1.f / 30.f);
            float z = ws[OFF_SOB];
            z += ga0 * ws[OFF_SOW + 0];
            z += ga1 * ws[OFF_SOW + 1];
            z += ga2 * ws[OFF_SOW + 2];
            z += emit * ws[OFF_SOW + 3];
            float sc = 1.f / (1.f + expf(-z));
            if (bf) ((__hip_bfloat16*)out)[1 + n] = __float2bfloat16(sc);
            else    ((float*)out)[1 + n] = sc;
        }
    }
}

// ---------------- kernel 3: doc-level head ----------------
__global__ __launch_bounds__(256) void k_final(const void* docgaf_in, void* out, const float* ws) {
    const int tid = threadIdx.x;
    const int bf = ((const int*)ws)[0];
    __shared__ float red[256];
    float m = -1e30f;
    for (int i = tid; i < 4000; i += 256) {
        float v = bf ? __bfloat162float(((const __hip_bfloat16*)out)[1 + i])
                     : ((const float*)out)[1 + i];
        m = fmaxf(m, v);
    }
    red[tid] = m;
    __syncthreads();
    for (int off = 128; off > 0; off >>= 1) {
        if (tid < off) red[tid] = fmaxf(red[tid], red[tid + off]);
        __syncthreads();
    }
    if (tid == 0) {
        float f = ws[OFF_FLB] + red[0] * ws[OFF_FLW + 0];
        for (int i = 0; i < 4; ++i) f += ldx(docgaf_in, i, bf) * ws[OFF_FLW + 1 + i];
        if (bf) ((__hip_bfloat16*)out)[0] = __float2bfloat16(f);
        else    ((float*)out)[0] = f;
    }
}

extern "C" void kernel_launch(void* const* d_in, const int* in_sizes, int n_in,
                              void* d_out, int out_size, void* d_ws, size_t ws_size,
                              hipStream_t stream) {
    float* ws = (float*)d_ws;
    k_prep<<<3, 256, 0, stream>>>(d_in[0], d_in[2], d_in[3], d_in[5], d_in[6], d_in[7], d_in[8],
                                  d_in[9], d_in[10], d_in[11], d_in[12], d_in[13], d_in[14],
                                  d_in[15], d_in[16], d_in[17], d_in[18], ws);
    k_main<<<4000, 128, 0, stream>>>(d_in[0], d_in[1], d_out, ws);
    k_final<<<1, 256, 0, stream>>>(d_in[4], d_out, ws);
}

// Round 10
// 179.599 us; speedup vs baseline: 1.1671x; 1.0675x over previous
//
#include <hip/hip_runtime.h>
#include <hip/hip_bf16.h>

#define SLOPE 0.1f

// ---- ws int-index layout: [0]=bf flag ----
// ---- ws float-index layout ----
#define OFF_QW    1816    // 30   q_weights (softmax)
#define OFF_QNI   1846    // 30   1/||QE[q]||
#define OFF_QNS   1876    // 30   1/||QC[q]||
#define OFF_QNN   1906    // 30   ||QE[q]|| (one-hot threshold)
#define OFF_B1    4606    // 30
#define OFF_B2    7336    // 30
#define OFF_LQ1W  7366    // 48
#define OFF_LQ1B  7414    // 8
#define OFF_LQ2W  7422    // 8
#define OFF_LQ2B  7430    // 1
#define OFF_SOW   7431    // 4
#define OFF_SOB   7435    // 1
#define OFF_FLW   7436    // 5
#define OFF_FLB   7441    // 1
// ---- bf16 (u16-index) region, starts at byte 32768 ----
#define U16_QEA   16384   // 32 rows x 32  (B-operand QE, zeros at d>=30, q>=30)
#define U16_QCA   17408   // 32 rows x 32  (B-operand QC)
#define U16_WB1   18432   // 32 rows x 96  (B-operand conv1 W[o][kk], kk=k*30+i)
#define U16_WB2   21504   // 32 rows x 96

typedef __attribute__((ext_vector_type(8))) __bf16 bf16x8;
typedef __attribute__((ext_vector_type(4))) float f32x4;

union Frag { uint4 u4; uint u[4]; bf16x8 v; };

__device__ __forceinline__ float bf2f(ushort h) {
    union { uint u; float f; } c; c.u = ((uint)h) << 16; return c.f;
}
__device__ __forceinline__ ushort f2bf(float f) {   // RNE, finite inputs
    union { float f; uint u; } c; c.f = f;
    uint u = c.u;
    return (ushort)((u + 0x7FFFu + ((u >> 16) & 1u)) >> 16);
}
__device__ __forceinline__ float ldx(const void* p, long i, int bf) {
    if (bf) return bf2f(((const ushort*)p)[i]);
    return ((const float*)p)[i];
}
#define CE(x, y) { float _hi = fmaxf(x, y), _lo = fminf(x, y); x = _hi; y = _lo; }

__device__ __forceinline__ void sort4d(float& a, float& b, float& c, float& d) {
    CE(a, b); CE(c, d); CE(a, c); CE(b, d); CE(b, c);
}
// merge two sorted-desc 4-lists -> top5 desc
__device__ __forceinline__ void merge44_5(const float* a, const float* b, float* t) {
    t[0] = fmaxf(a[0], b[0]);
    t[1] = fmaxf(fminf(a[0], b[0]), fmaxf(a[1], b[1]));
    t[2] = fmaxf(fmaxf(fminf(a[0], b[1]), fminf(a[1], b[0])), fmaxf(a[2], b[2]));
    t[3] = fmaxf(fmaxf(fminf(a[0], b[2]), fminf(a[1], b[1])),
                 fmaxf(fminf(a[2], b[0]), fmaxf(a[3], b[3])));
    t[4] = fmaxf(fmaxf(fminf(a[0], b[3]), fminf(a[1], b[2])),
                 fmaxf(fminf(a[2], b[1]), fminf(a[3], b[0])));
}
// merge sorted5 + sorted4 -> top5
__device__ __forceinline__ void merge54_5(const float* a, const float* b, float* t) {
    t[0] = fmaxf(a[0], b[0]);
    t[1] = fmaxf(fminf(a[0], b[0]), fmaxf(a[1], b[1]));
    t[2] = fmaxf(fmaxf(fminf(a[0], b[1]), fminf(a[1], b[0])), fmaxf(a[2], b[2]));
    t[3] = fmaxf(fmaxf(fminf(a[0], b[2]), fminf(a[1], b[1])),
                 fmaxf(fminf(a[2], b[0]), fmaxf(a[3], b[3])));
    t[4] = fmaxf(fmaxf(fmaxf(fminf(a[0], b[3]), fminf(a[1], b[2])),
                       fmaxf(fminf(a[2], b[1]), fminf(a[3], b[0]))), a[4]);
}
// merge two sorted5 -> top5
__device__ __forceinline__ void merge55_5(const float* a, const float* b, float* t) {
    t[0] = fmaxf(a[0], b[0]);
    t[1] = fmaxf(fminf(a[0], b[0]), fmaxf(a[1], b[1]));
    t[2] = fmaxf(fmaxf(fminf(a[0], b[1]), fminf(a[1], b[0])), fmaxf(a[2], b[2]));
    t[3] = fmaxf(fmaxf(fminf(a[0], b[2]), fminf(a[1], b[1])),
                 fmaxf(fminf(a[2], b[0]), fmaxf(a[3], b[3])));
    t[4] = fmaxf(fmaxf(fmaxf(fminf(a[0], b[3]), fminf(a[1], b[2])),
                       fmaxf(fminf(a[2], b[1]), fminf(a[3], b[0]))),
                 fmaxf(a[4], b[4]));
}

// dtype detection: f32 mantissa words carry wild bf16-exponent fields
__device__ __forceinline__ int detect_bf(const void* doc_in, int tid, int* scnt) {
    if (tid == 0) *scnt = 0;
    __syncthreads();
    const ushort* p = (const ushort*)doc_in;
    int local = 0;
    for (int i = tid; i < 4096; i += 256) {
        unsigned e = (p[i] >> 7) & 0xFFu;
        if (e != 0u && (e < 100u || e > 134u)) local++;
    }
    atomicAdd(scnt, local);
    __syncthreads();
    return (*scnt > 200) ? 0 : 1;
}

// ---------------- kernel 1 (3 blocks): detect + question path + repack ----------------
__global__ __launch_bounds__(256) void k_prep(
        const void* doc_in,
        const void* qe_in, const void* qidf_in,
        const void* w1_in, const void* b1_in,
        const void* w2_in, const void* b2_in,
        const void* qwW_in, const void* qwb_in,
        const void* lq1W_in, const void* lq1b_in,
        const void* lq2W_in, const void* lq2b_in,
        const void* soW_in, const void* sob_in,
        const void* flW_in, const void* flb_in,
        float* ws) {
    const int tid = threadIdx.x;
    const int blk = blockIdx.x;
    __shared__ float QE[900], T1[900], QC[900], W[2700], IDF[32], LG[32];
    __shared__ int scnt;

    const int bf = detect_bf(doc_in, tid, &scnt);
    ushort* wsu = (ushort*)ws;

    if (blk == 1) {
        if (tid == 0) { ((int*)ws)[0] = bf; }
        if (tid < 30) ws[OFF_B1 + tid] = ldx(b1_in, tid, bf);
        if (tid < 48) ws[OFF_LQ1W + tid] = ldx(lq1W_in, tid, bf);
        if (tid < 8)  { ws[OFF_LQ1B + tid] = ldx(lq1b_in, tid, bf);
                        ws[OFF_LQ2W + tid] = ldx(lq2W_in, tid, bf); }
        if (tid < 4)  ws[OFF_SOW + tid] = ldx(soW_in, tid, bf);
        if (tid < 5)  ws[OFF_FLW + tid] = ldx(flW_in, tid, bf);
        if (tid == 1) { ws[OFF_LQ2B] = ldx(lq2b_in, 0, bf);
                        ws[OFF_SOB]  = ldx(sob_in, 0, bf);
                        ws[OFF_FLB]  = ldx(flb_in, 0, bf); }
        for (int i = tid; i < 3072; i += 256) {
            int o = i / 96, kk = i % 96;
            float v1 = 0.f;
            if (o < 30 && kk < 90) {
                int ii = kk % 30, k = kk / 30;
                v1 = ldx(w1_in, (long)o*90 + ii*3 + k, bf);
            }
            wsu[U16_WB1 + i] = f2bf(v1);
        }
        return;
    }
    if (blk == 2) {
        if (tid < 30) ws[OFF_B2 + tid] = ldx(b2_in, tid, bf);
        for (int i = tid; i < 3072; i += 256) {
            int o = i / 96, kk = i % 96;
            float v2 = 0.f;
            if (o < 30 && kk < 90) {
                int ii = kk % 30, k = kk / 30;
                v2 = ldx(w2_in, (long)o*90 + ii*3 + k, bf);
            }
            wsu[U16_WB2 + i] = f2bf(v2);
        }
        return;
    }

    // ---- block 0: control word + question path ----
    if (tid == 0) { ((int*)ws)[0] = bf; }

    for (int i = tid; i < 900; i += 256) QE[i] = ldx(qe_in, i, bf);
    if (tid < 30) IDF[tid] = ldx(qidf_in, tid, bf);
    for (int i = tid; i < 2700; i += 256) W[i] = ldx(w1_in, i, bf);
    __syncthreads();

    for (int idx = tid; idx < 900; idx += 256) {
        int s = idx / 30, o = idx % 30;
        float acc = ldx(b1_in, o, bf);
        for (int k = 0; k < 3; ++k) {
            int t = s + k - 1;
            if (t < 0 || t >= 30) continue;
            for (int i = 0; i < 30; ++i) acc += QE[t*30 + i] * W[o*90 + i*3 + k];
        }
        acc = acc >= 0.f ? acc : SLOPE * acc;
        T1[idx] = acc + QE[idx];
    }
    __syncthreads();
    for (int i = tid; i < 2700; i += 256) W[i] = ldx(w2_in, i, bf);
    __syncthreads();
    for (int idx = tid; idx < 900; idx += 256) {
        int s = idx / 30, o = idx % 30;
        float acc = ldx(b2_in, o, bf);
        for (int k = 0; k < 3; ++k) {
            int t = s + k - 1;
            if (t < 0 || t >= 30) continue;
            for (int i = 0; i < 30; ++i) acc += T1[t*30 + i] * W[o*90 + i*3 + k];
        }
        acc = acc >= 0.f ? acc : SLOPE * acc;
        QC[idx] = acc + T1[idx];
    }
    __syncthreads();

    if (tid < 30) {
        float s1 = 0.f, s2 = 0.f;
        for (int d = 0; d < 30; ++d) {
            float a = QE[tid*30 + d]; s1 += a*a;
            float b = QC[tid*30 + d]; s2 += b*b;
        }
        float n1 = sqrtf(s1);
        ws[OFF_QNN + tid] = n1;
        ws[OFF_QNI + tid] = 1.0f / n1;
        ws[OFF_QNS + tid] = 1.0f / sqrtf(s2);
        float z = ldx(qwb_in, 0, bf);
        for (int d = 0; d < 30; ++d) z += QC[tid*30 + d] * ldx(qwW_in, d, bf);
        z += IDF[tid] * ldx(qwW_in, 30, bf);
        LG[tid] = z;
    }
    __syncthreads();
    if (tid == 0) {
        float m = -1e30f;
        for (int q = 0; q < 30; ++q) m = fmaxf(m, LG[q]);
        float sum = 0.f, e[30];
        for (int q = 0; q < 30; ++q) { e[q] = expf(LG[q] - m); sum += e[q]; }
        for (int q = 0; q < 30; ++q) ws[OFF_QW + q] = e[q] / sum;
    }
    for (int i = tid; i < 1024; i += 256) {
        int q = i >> 5, d = i & 31;
        float ve = (q < 30 && d < 30) ? QE[q*30 + d] : 0.f;
        float vc = (q < 30 && d < 30) ? QC[q*30 + d] : 0.f;
        wsu[U16_QEA + i] = f2bf(ve);
        wsu[U16_QCA + i] = f2bf(vc);
    }
}

// ---------------- kernel 2: per-sentence fused MFMA pipeline (R7 structure) ----------------
// 2 cooperating waves per sentence. LDS row layout: 16-dword zero header
// (row s=-1, keeps uint4 staging 16B-aligned), row s at dword 16+s*15,
// dwords [1516,1546) zero (rows 100/101 for the conv window).
__global__ __launch_bounds__(128, 4) void k_main(const void* doc_in, const void* gaf_in,
                                                 void* out, float* ws) {
    const int n = blockIdx.x;
    const int tid = threadIdx.x;
    const int bf = ((const int*)ws)[0];
    const int lane = tid & 63;
    const int wid = tid >> 6;          // 0 or 1
    const int l15 = lane & 15;
    const int quad = lane >> 4;

    __shared__ __align__(16) uint XA32[1546];
    __shared__ __align__(16) uint XB32[1546];
    __shared__ __align__(16) float INVX[112];   // [100,112) zero pad
    __shared__ float FE[30][6];
    __shared__ float IQI[32], IQS[32], QNN[32], BI1[32], BI2[32];

    ushort* XAu = (ushort*)XA32;
    const ushort* wsu = (const ushort*)ws;
    const uint4* qeA = (const uint4*)(wsu + U16_QEA);
    const uint4* qcA = (const uint4*)(wsu + U16_QCA);
    const uint4* wb1 = (const uint4*)(wsu + U16_WB1);
    const uint4* wb2 = (const uint4*)(wsu + U16_WB2);

    // prefetch gaf scalars (consumed at the very end by wave0 lane0)
    float ga0 = ldx(gaf_in, (long)n*3 + 0, bf);
    float ga1 = ldx(gaf_in, (long)n*3 + 1, bf);
    float ga2 = ldx(gaf_in, (long)n*3 + 2, bf);

    // ---- B0: zero pads, load sentence (uint4), cache small params in LDS ----
    for (int i = tid; i < 46; i += 128) {
        int j = (i < 16) ? i : (1500 + i);   // [0,16) and [1516,1546)
        XA32[j] = 0u; XB32[j] = 0u;
    }
    if (tid >= 100 && tid < 112) INVX[tid] = 0.f;
    if (bf) {
        const uint4* g = (const uint4*)((const ushort*)doc_in + (size_t)n * 3000);
        uint4* dst = (uint4*)(XA32 + 16);          // byte 64: 16B-aligned
        for (int i = tid; i < 375; i += 128) dst[i] = g[i];
    } else {
        const float* p = (const float*)doc_in + (size_t)n * 3000;
        for (int i = tid; i < 3000; i += 128) XAu[32 + i] = f2bf(p[i]);
    }
    if (tid < 32) {
        IQI[tid] = (tid < 30) ? ws[OFF_QNI + tid] : 0.f;
        IQS[tid] = (tid < 30) ? ws[OFF_QNS + tid] : 0.f;
        QNN[tid] = (tid < 30) ? ws[OFF_QNN + tid] : 0.f;
        BI1[tid] = (tid < 30) ? ws[OFF_B1 + tid] : 0.f;
        BI2[tid] = (tid < 30) ? ws[OFF_B2 + tid] : 0.f;
    }
    __syncthreads();

    // ---- inverse row norms ----
    auto norms = [&](const uint* src) {
        if (tid < 100) {
            const uint* r = src + 16 + tid * 15;
            float s = 0.f;
            #pragma unroll
            for (int i = 0; i < 15; ++i) {
                uint u = r[i];
                float lo = __uint_as_float(u << 16);
                float hi = __uint_as_float(u & 0xFFFF0000u);
                s += lo * lo + hi * hi;
            }
            INVX[tid] = 1.f / sqrtf(s);
        }
    };
    norms(XA32);
    __syncthreads();

    // transposed sim + in-lane pool; lane owns q = wid*16 + l15
    auto sim_pool = [&](const uint4* qa, const float* IQ, int fbase, bool do_oh) {
        const int q = wid * 16 + l15;
        Frag b;
        b.u4 = qa[q * 4 + quad];            // B[k=quad*8+j][n=q] == Q[q][k] table row
        f32x4 acc[7];
        #pragma unroll
        for (int mt = 0; mt < 7; ++mt) {
            int m = mt * 16 + l15;          // s-row of A
            Frag a;
            if (m < 100) {
                int base = 16 + m * 15 + quad * 4;
                a.u[0] = XA32[base];     a.u[1] = XA32[base + 1];
                a.u[2] = XA32[base + 2]; a.u[3] = XA32[base + 3];
            } else { a.u[0] = a.u[1] = a.u[2] = a.u[3] = 0u; }
            f32x4 z = {0.f, 0.f, 0.f, 0.f};
            acc[mt] = __builtin_amdgcn_mfma_f32_16x16x32_bf16(a.v, b.v, z, 0, 0, 0);
        }
        // u[s] = num * invx[s]; s = mt*16 + quad*4 + r (in-lane)
        const float4* INVX4 = (const float4*)INVX;
        float thr = 0.999f * QNN[q];        // u > thr  <=>  sim > 0.999
        float iq  = (q < 30) ? IQ[q] : 0.f;
        float g[7][4];
        int cnt = 0;
        #pragma unroll
        for (int mt = 0; mt < 7; ++mt) {
            float4 ix = INVX4[mt * 4 + quad];
            float ixa[4] = {ix.x, ix.y, ix.z, ix.w};
            #pragma unroll
            for (int r = 0; r < 4; ++r) {
                float u = acc[mt][r] * ixa[r];
                if (mt == 6 && (quad * 4 + r) >= 4) u = -1e30f;   // s >= 100
                g[mt][r] = u;
                if (do_oh) cnt += (u > thr) ? 1 : 0;
            }
        }
        // in-lane top5-of-28: 7x sort4 + capped merge tree
        #pragma unroll
        for (int mt = 0; mt < 7; ++mt) sort4d(g[mt][0], g[mt][1], g[mt][2], g[mt][3]);
        float p0[5], p1[5], p2[5], q0[5], q1[5], t[5];
        merge44_5(g[0], g[1], p0);
        merge44_5(g[2], g[3], p1);
        merge44_5(g[4], g[5], p2);
        merge55_5(p0, p1, q0);
        merge54_5(p2, g[6], q1);
        merge55_5(q0, q1, t);
        // butterfly across the 4 quads (lanes xor 16, 32; l15 preserved)
        #pragma unroll
        for (int d = 16; d < 64; d <<= 1) {
            float pp[5];
            pp[0] = __shfl_xor(t[0], d); pp[1] = __shfl_xor(t[1], d);
            pp[2] = __shfl_xor(t[2], d); pp[3] = __shfl_xor(t[3], d);
            pp[4] = __shfl_xor(t[4], d);
            if (do_oh) cnt += __shfl_xor(cnt, d);
            float tn[5];
            merge55_5(t, pp, tn);
            t[0] = tn[0]; t[1] = tn[1]; t[2] = tn[2]; t[3] = tn[3]; t[4] = tn[4];
        }
        if (quad == 0 && q < 30) {
            if (do_oh) {
                FE[q][0] = cnt > 0 ? 1.f : 0.f;
                FE[q][1] = (float)(cnt > 5 ? 5 : cnt) * 0.2f;
            }
            FE[q][fbase]     = t[0] * iq;
            FE[q][fbase + 1] = (t[0] + t[1] + t[2] + t[3] + t[4]) * 0.2f * iq;
        }
    };

    // conv for one mt; A-fragments shared across nt tiles [nt0, nt1];
    // bias enters through the MFMA C operand (broadcast across the acc row).
    auto conv_mt = [&](const uint* src32, uint* dst32, const uint4* wb,
                       const float* bias, int mt, int nt0, int nt1) {
        const ushort* srcU = (const ushort*)src32;
        ushort* dstU = (ushort*)dst32;
        int sa = mt * 16 + l15;
        Frag a[3];
        #pragma unroll
        for (int k = 0; k < 3; ++k) {
            if (sa < 100) {
                int base = 16 + (sa - 1) * 15 + k * 16 + quad * 4;
                a[k].u[0] = src32[base];     a[k].u[1] = src32[base + 1];
                a[k].u[2] = src32[base + 2]; a[k].u[3] = src32[base + 3];
            } else { a[k].u[0] = a[k].u[1] = a[k].u[2] = a[k].u[3] = 0u; }
        }
        for (int nt = nt0; nt <= nt1; ++nt) {
            int o = nt * 16 + l15;
            float bo = bias[o];                        // 0 for o >= 30
            f32x4 acc = {bo, bo, bo, bo};
            #pragma unroll
            for (int k = 0; k < 3; ++k) {
                Frag b;
                b.u4 = wb[o * 12 + k * 4 + quad];
                acc = __builtin_amdgcn_mfma_f32_16x16x32_bf16(a[k].v, b.v, acc, 0, 0, 0);
            }
            if (o < 30) {
                #pragma unroll
                for (int r = 0; r < 4; ++r) {
                    int s = mt * 16 + quad * 4 + r;
                    if (s < 100) {
                        float v = acc[r];
                        v = v >= 0.f ? v : SLOPE * v;
                        v += bf2f(srcU[32 + s * 30 + o]);
                        dstU[32 + s * 30 + o] = f2bf(v);
                    }
                }
            }
        }
    };

    // ---- B2: sim_insens + pool then conv1 XA->XB ----
    sim_pool(qeA, IQI, 2, true);
    conv_mt(XA32, XB32, wb1, BI1, wid,     0, 1);
    conv_mt(XA32, XB32, wb1, BI1, wid + 2, 0, 1);
    conv_mt(XA32, XB32, wb1, BI1, wid + 4, 0, 1);
    conv_mt(XA32, XB32, wb1, BI1, 6,       wid, wid);
    __syncthreads();

    // ---- B3: conv2 XB->XA ----
    conv_mt(XB32, XA32, wb2, BI2, wid,     0, 1);
    conv_mt(XB32, XA32, wb2, BI2, wid + 2, 0, 1);
    conv_mt(XB32, XA32, wb2, BI2, wid + 4, 0, 1);
    conv_mt(XB32, XA32, wb2, BI2, 6,       wid, wid);
    __syncthreads();

    // ---- B4: inverse row norms of conv_res ----
    norms(XA32);
    __syncthreads();

    // ---- B5: sim_sens + pool ----
    sim_pool(qcA, IQS, 4, false);
    __syncthreads();

    // ---- B6: wave0: per-q MLP, butterfly-sum, score write ----
    if (wid == 0) {
        float val = 0.f;
        if (lane < 30) {
            float lo = ws[OFF_LQ2B];
            #pragma unroll
            for (int j = 0; j < 8; ++j) {
                float h = ws[OFF_LQ1B + j];
                #pragma unroll
                for (int f = 0; f < 6; ++f) h += FE[lane][f] * ws[OFF_LQ1W + j*6 + f];
                h = h >= 0.f ? h : SLOPE * h;
                lo += h * ws[OFF_LQ2W + j];
            }
            val = lo * ws[OFF_QW + lane];
        }
        for (int d = 32; d >= 1; d >>= 1) val += __shfl_xor(val, d);
        if (lane == 0) {
            float emit = val * (1.f / 30.f);
            float z = ws[OFF_SOB];
            z += ga0 * ws[OFF_SOW + 0];
            z += ga1 * ws[OFF_SOW + 1];
            z += ga2 * ws[OFF_SOW + 2];
            z += emit * ws[OFF_SOW + 3];
            float sc = 1.f / (1.f + expf(-z));
            if (bf) ((__hip_bfloat16*)out)[1 + n] = __float2bfloat16(sc);
            else    ((float*)out)[1 + n] = sc;
        }
    }
}

// ---------------- kernel 3: doc-level head ----------------
__global__ __launch_bounds__(256) void k_final(const void* docgaf_in, void* out, const float* ws) {
    const int tid = threadIdx.x;
    const int bf = ((const int*)ws)[0];
    __shared__ float red[256];
    float m = -1e30f;
    for (int i = tid; i < 4000; i += 256) {
        float v = bf ? __bfloat162float(((const __hip_bfloat16*)out)[1 + i])
                     : ((const float*)out)[1 + i];
        m = fmaxf(m, v);
    }
    red[tid] = m;
    __syncthreads();
    for (int off = 128; off > 0; off >>= 1) {
        if (tid < off) red[tid] = fmaxf(red[tid], red[tid + off]);
        __syncthreads();
    }
    if (tid == 0) {
        float f = ws[OFF_FLB] + red[0] * ws[OFF_FLW + 0];
        for (int i = 0; i < 4; ++i) f += ldx(docgaf_in, i, bf) * ws[OFF_FLW + 1 + i];
        if (bf) ((__hip_bfloat16*)out)[0] = __float2bfloat16(f);
        else    ((float*)out)[0] = f;
    }
}

extern "C" void kernel_launch(void* const* d_in, const int* in_sizes, int n_in,
                              void* d_out, int out_size, void* d_ws, size_t ws_size,
                              hipStream_t stream) {
    float* ws = (float*)d_ws;
    k_prep<<<3, 256, 0, stream>>>(d_in[0], d_in[2], d_in[3], d_in[5], d_in[6], d_in[7], d_in[8],
                                  d_in[9], d_in[10], d_in[11], d_in[12], d_in[13], d_in[14],
                                  d_in[15], d_in[16], d_in[17], d_in[18], ws);
    k_main<<<4000, 128, 0, stream>>>(d_in[0], d_in[1], d_out, ws);
    k_final<<<1, 256, 0, stream>>>(d_in[4], d_out, ws);
}

// Round 11
// 177.065 us; speedup vs baseline: 1.1839x; 1.0143x over previous
//
#include <hip/hip_runtime.h>
#include <hip/hip_bf16.h>

#define SLOPE 0.1f

// ---- ws int-index layout: [0]=bf flag ----
// ---- ws float-index layout ----
#define OFF_QW    1816    // 30   q_weights (softmax)
#define OFF_QNI   1846    // 30   1/||QE[q]||
#define OFF_QNS   1876    // 30   1/||QC[q]||
#define OFF_QNN   1906    // 30   ||QE[q]|| (one-hot threshold)
#define OFF_B1    4606    // 30
#define OFF_B2    7336    // 30
#define OFF_LQ1W  7366    // 48
#define OFF_LQ1B  7414    // 8
#define OFF_LQ2W  7422    // 8
#define OFF_LQ2B  7430    // 1
#define OFF_SOW   7431    // 4
#define OFF_SOB   7435    // 1
#define OFF_FLW   7436    // 5
#define OFF_FLB   7441    // 1
// ---- bf16 (u16-index) region, starts at byte 32768 ----
#define U16_QEA   16384   // 32 rows x 32  (B-operand QE, zeros at d>=30, q>=30)
#define U16_QCA   17408   // 32 rows x 32  (B-operand QC)
#define U16_WB1   18432   // 32 rows x 96  (B-operand conv1 W[o][kk], kk=k*30+i)
#define U16_WB2   21504   // 32 rows x 96

typedef __attribute__((ext_vector_type(8))) __bf16 bf16x8;
typedef __attribute__((ext_vector_type(4))) float f32x4;

union Frag { uint4 u4; uint u[4]; bf16x8 v; };

__device__ __forceinline__ float bf2f(ushort h) {
    union { uint u; float f; } c; c.u = ((uint)h) << 16; return c.f;
}
__device__ __forceinline__ ushort f2bf(float f) {   // RNE, finite inputs
    union { float f; uint u; } c; c.f = f;
    uint u = c.u;
    return (ushort)((u + 0x7FFFu + ((u >> 16) & 1u)) >> 16);
}
__device__ __forceinline__ ushort f2bf_tr(float f) {  // truncate (conv intermediates only)
    union { float f; uint u; } c; c.f = f;
    return (ushort)(c.u >> 16);
}
__device__ __forceinline__ float ldx(const void* p, long i, int bf) {
    if (bf) return bf2f(((const ushort*)p)[i]);
    return ((const float*)p)[i];
}
#define CE(x, y) { float _hi = fmaxf(x, y), _lo = fminf(x, y); x = _hi; y = _lo; }

__device__ __forceinline__ void sort4d(float& a, float& b, float& c, float& d) {
    CE(a, b); CE(c, d); CE(a, c); CE(b, d); CE(b, c);
}
// merge two sorted-desc 4-lists -> top5 desc
__device__ __forceinline__ void merge44_5(const float* a, const float* b, float* t) {
    t[0] = fmaxf(a[0], b[0]);
    t[1] = fmaxf(fminf(a[0], b[0]), fmaxf(a[1], b[1]));
    t[2] = fmaxf(fmaxf(fminf(a[0], b[1]), fminf(a[1], b[0])), fmaxf(a[2], b[2]));
    t[3] = fmaxf(fmaxf(fminf(a[0], b[2]), fminf(a[1], b[1])),
                 fmaxf(fminf(a[2], b[0]), fmaxf(a[3], b[3])));
    t[4] = fmaxf(fmaxf(fminf(a[0], b[3]), fminf(a[1], b[2])),
                 fmaxf(fminf(a[2], b[1]), fminf(a[3], b[0])));
}
// merge sorted5 + sorted4 -> top5
__device__ __forceinline__ void merge54_5(const float* a, const float* b, float* t) {
    t[0] = fmaxf(a[0], b[0]);
    t[1] = fmaxf(fminf(a[0], b[0]), fmaxf(a[1], b[1]));
    t[2] = fmaxf(fmaxf(fminf(a[0], b[1]), fminf(a[1], b[0])), fmaxf(a[2], b[2]));
    t[3] = fmaxf(fmaxf(fminf(a[0], b[2]), fminf(a[1], b[1])),
                 fmaxf(fminf(a[2], b[0]), fmaxf(a[3], b[3])));
    t[4] = fmaxf(fmaxf(fmaxf(fminf(a[0], b[3]), fminf(a[1], b[2])),
                       fmaxf(fminf(a[2], b[1]), fminf(a[3], b[0]))), a[4]);
}
// merge two sorted5 -> top5
__device__ __forceinline__ void merge55_5(const float* a, const float* b, float* t) {
    t[0] = fmaxf(a[0], b[0]);
    t[1] = fmaxf(fminf(a[0], b[0]), fmaxf(a[1], b[1]));
    t[2] = fmaxf(fmaxf(fminf(a[0], b[1]), fminf(a[1], b[0])), fmaxf(a[2], b[2]));
    t[3] = fmaxf(fmaxf(fminf(a[0], b[2]), fminf(a[1], b[1])),
                 fmaxf(fminf(a[2], b[0]), fmaxf(a[3], b[3])));
    t[4] = fmaxf(fmaxf(fmaxf(fminf(a[0], b[3]), fminf(a[1], b[2])),
                       fmaxf(fminf(a[2], b[1]), fminf(a[3], b[0]))),
                 fmaxf(a[4], b[4]));
}

// dtype detection: f32 mantissa words carry wild bf16-exponent fields
__device__ __forceinline__ int detect_bf(const void* doc_in, int tid, int* scnt) {
    if (tid == 0) *scnt = 0;
    __syncthreads();
    const ushort* p = (const ushort*)doc_in;
    int local = 0;
    for (int i = tid; i < 4096; i += 256) {
        unsigned e = (p[i] >> 7) & 0xFFu;
        if (e != 0u && (e < 100u || e > 134u)) local++;
    }
    atomicAdd(scnt, local);
    __syncthreads();
    return (*scnt > 200) ? 0 : 1;
}

// ---------------- kernel 1 (3 blocks): detect + question path + repack ----------------
__global__ __launch_bounds__(256) void k_prep(
        const void* doc_in,
        const void* qe_in, const void* qidf_in,
        const void* w1_in, const void* b1_in,
        const void* w2_in, const void* b2_in,
        const void* qwW_in, const void* qwb_in,
        const void* lq1W_in, const void* lq1b_in,
        const void* lq2W_in, const void* lq2b_in,
        const void* soW_in, const void* sob_in,
        const void* flW_in, const void* flb_in,
        float* ws) {
    const int tid = threadIdx.x;
    const int blk = blockIdx.x;
    __shared__ float QE[900], T1[900], QC[900], W[2700], IDF[32], LG[32];
    __shared__ int scnt;

    const int bf = detect_bf(doc_in, tid, &scnt);
    ushort* wsu = (ushort*)ws;

    if (blk == 1) {
        if (tid == 0) { ((int*)ws)[0] = bf; }
        if (tid < 30) ws[OFF_B1 + tid] = ldx(b1_in, tid, bf);
        if (tid < 48) ws[OFF_LQ1W + tid] = ldx(lq1W_in, tid, bf);
        if (tid < 8)  { ws[OFF_LQ1B + tid] = ldx(lq1b_in, tid, bf);
                        ws[OFF_LQ2W + tid] = ldx(lq2W_in, tid, bf); }
        if (tid < 4)  ws[OFF_SOW + tid] = ldx(soW_in, tid, bf);
        if (tid < 5)  ws[OFF_FLW + tid] = ldx(flW_in, tid, bf);
        if (tid == 1) { ws[OFF_LQ2B] = ldx(lq2b_in, 0, bf);
                        ws[OFF_SOB]  = ldx(sob_in, 0, bf);
                        ws[OFF_FLB]  = ldx(flb_in, 0, bf); }
        for (int i = tid; i < 3072; i += 256) {
            int o = i / 96, kk = i % 96;
            float v1 = 0.f;
            if (o < 30 && kk < 90) {
                int ii = kk % 30, k = kk / 30;
                v1 = ldx(w1_in, (long)o*90 + ii*3 + k, bf);
            }
            wsu[U16_WB1 + i] = f2bf(v1);
        }
        return;
    }
    if (blk == 2) {
        if (tid < 30) ws[OFF_B2 + tid] = ldx(b2_in, tid, bf);
        for (int i = tid; i < 3072; i += 256) {
            int o = i / 96, kk = i % 96;
            float v2 = 0.f;
            if (o < 30 && kk < 90) {
                int ii = kk % 30, k = kk / 30;
                v2 = ldx(w2_in, (long)o*90 + ii*3 + k, bf);
            }
            wsu[U16_WB2 + i] = f2bf(v2);
        }
        return;
    }

    // ---- block 0: control word + question path ----
    if (tid == 0) { ((int*)ws)[0] = bf; }

    for (int i = tid; i < 900; i += 256) QE[i] = ldx(qe_in, i, bf);
    if (tid < 30) IDF[tid] = ldx(qidf_in, tid, bf);
    for (int i = tid; i < 2700; i += 256) W[i] = ldx(w1_in, i, bf);
    __syncthreads();

    for (int idx = tid; idx < 900; idx += 256) {
        int s = idx / 30, o = idx % 30;
        float acc = ldx(b1_in, o, bf);
        for (int k = 0; k < 3; ++k) {
            int t = s + k - 1;
            if (t < 0 || t >= 30) continue;
            for (int i = 0; i < 30; ++i) acc += QE[t*30 + i] * W[o*90 + i*3 + k];
        }
        acc = acc >= 0.f ? acc : SLOPE * acc;
        T1[idx] = acc + QE[idx];
    }
    __syncthreads();
    for (int i = tid; i < 2700; i += 256) W[i] = ldx(w2_in, i, bf);
    __syncthreads();
    for (int idx = tid; idx < 900; idx += 256) {
        int s = idx / 30, o = idx % 30;
        float acc = ldx(b2_in, o, bf);
        for (int k = 0; k < 3; ++k) {
            int t = s + k - 1;
            if (t < 0 || t >= 30) continue;
            for (int i = 0; i < 30; ++i) acc += T1[t*30 + i] * W[o*90 + i*3 + k];
        }
        acc = acc >= 0.f ? acc : SLOPE * acc;
        QC[idx] = acc + T1[idx];
    }
    __syncthreads();

    if (tid < 30) {
        float s1 = 0.f, s2 = 0.f;
        for (int d = 0; d < 30; ++d) {
            float a = QE[tid*30 + d]; s1 += a*a;
            float b = QC[tid*30 + d]; s2 += b*b;
        }
        float n1 = sqrtf(s1);
        ws[OFF_QNN + tid] = n1;
        ws[OFF_QNI + tid] = 1.0f / n1;
        ws[OFF_QNS + tid] = 1.0f / sqrtf(s2);
        float z = ldx(qwb_in, 0, bf);
        for (int d = 0; d < 30; ++d) z += QC[tid*30 + d] * ldx(qwW_in, d, bf);
        z += IDF[tid] * ldx(qwW_in, 30, bf);
        LG[tid] = z;
    }
    __syncthreads();
    if (tid == 0) {
        float m = -1e30f;
        for (int q = 0; q < 30; ++q) m = fmaxf(m, LG[q]);
        float sum = 0.f, e[30];
        for (int q = 0; q < 30; ++q) { e[q] = expf(LG[q] - m); sum += e[q]; }
        for (int q = 0; q < 30; ++q) ws[OFF_QW + q] = e[q] / sum;
    }
    for (int i = tid; i < 1024; i += 256) {
        int q = i >> 5, d = i & 31;
        float ve = (q < 30 && d < 30) ? QE[q*30 + d] : 0.f;
        float vc = (q < 30 && d < 30) ? QC[q*30 + d] : 0.f;
        wsu[U16_QEA + i] = f2bf(ve);
        wsu[U16_QCA + i] = f2bf(vc);
    }
}

// ---------------- kernel 2: per-sentence fused MFMA pipeline (R10 structure) ----------------
// 2 cooperating waves per sentence. LDS row layout: 16-dword zero header
// (row s=-1, keeps uint4 staging 16B-aligned), row s at dword 16+s*15,
// dwords [1516,1546) zero (rows 100/101 for the conv window).
__global__ __launch_bounds__(128, 8) void k_main(const void* doc_in, const void* gaf_in,
                                                 void* out, float* ws) {
    const int n = blockIdx.x;
    const int tid = threadIdx.x;
    const int bf = ((const int*)ws)[0];
    const int lane = tid & 63;
    const int wid = tid >> 6;          // 0 or 1
    const int l15 = lane & 15;
    const int quad = lane >> 4;

    __shared__ __align__(16) uint XA32[1546];
    __shared__ __align__(16) uint XB32[1546];
    __shared__ __align__(16) float INVX[112];   // [100,112) zero pad
    __shared__ float FE[30][6];
    __shared__ float IQI[32], IQS[32], QNN[32], BI1[32], BI2[32];

    ushort* XAu = (ushort*)XA32;
    const ushort* wsu = (const ushort*)ws;
    const uint4* qeA = (const uint4*)(wsu + U16_QEA);
    const uint4* qcA = (const uint4*)(wsu + U16_QCA);
    const uint4* wb1 = (const uint4*)(wsu + U16_WB1);
    const uint4* wb2 = (const uint4*)(wsu + U16_WB2);

    // prefetch gaf scalars (consumed at the very end by wave0 lane0)
    float ga0 = ldx(gaf_in, (long)n*3 + 0, bf);
    float ga1 = ldx(gaf_in, (long)n*3 + 1, bf);
    float ga2 = ldx(gaf_in, (long)n*3 + 2, bf);

    // ---- B0: zero pads, load sentence (uint4), cache small params in LDS ----
    for (int i = tid; i < 46; i += 128) {
        int j = (i < 16) ? i : (1500 + i);   // [0,16) and [1516,1546)
        XA32[j] = 0u; XB32[j] = 0u;
    }
    if (tid >= 100 && tid < 112) INVX[tid] = 0.f;
    if (bf) {
        const uint4* g = (const uint4*)((const ushort*)doc_in + (size_t)n * 3000);
        uint4* dst = (uint4*)(XA32 + 16);          // byte 64: 16B-aligned
        for (int i = tid; i < 375; i += 128) dst[i] = g[i];
    } else {
        const float* p = (const float*)doc_in + (size_t)n * 3000;
        for (int i = tid; i < 3000; i += 128) XAu[32 + i] = f2bf(p[i]);
    }
    if (tid < 32) {
        IQI[tid] = (tid < 30) ? ws[OFF_QNI + tid] : 0.f;
        IQS[tid] = (tid < 30) ? ws[OFF_QNS + tid] : 0.f;
        QNN[tid] = (tid < 30) ? ws[OFF_QNN + tid] : 0.f;
        BI1[tid] = (tid < 30) ? ws[OFF_B1 + tid] : 0.f;
        BI2[tid] = (tid < 30) ? ws[OFF_B2 + tid] : 0.f;
    }
    __syncthreads();

    // ---- inverse row norms ----
    auto norms = [&](const uint* src) {
        if (tid < 100) {
            const uint* r = src + 16 + tid * 15;
            float s = 0.f;
            #pragma unroll
            for (int i = 0; i < 15; ++i) {
                uint u = r[i];
                float lo = __uint_as_float(u << 16);
                float hi = __uint_as_float(u & 0xFFFF0000u);
                s += lo * lo + hi * hi;
            }
            INVX[tid] = 1.f / sqrtf(s);
        }
    };
    norms(XA32);
    __syncthreads();

    // transposed sim + in-lane pool; lane owns q = wid*16 + l15
    auto sim_pool = [&](const uint4* qa, const float* IQ, int fbase, bool do_oh) {
        const int q = wid * 16 + l15;
        Frag b;
        b.u4 = qa[q * 4 + quad];            // B[k=quad*8+j][n=q] == Q[q][k] table row
        f32x4 acc[7];
        #pragma unroll
        for (int mt = 0; mt < 7; ++mt) {
            int m = mt * 16 + l15;          // s-row of A
            Frag a;
            if (m < 100) {
                int base = 16 + m * 15 + quad * 4;
                a.u[0] = XA32[base];     a.u[1] = XA32[base + 1];
                a.u[2] = XA32[base + 2]; a.u[3] = XA32[base + 3];
            } else { a.u[0] = a.u[1] = a.u[2] = a.u[3] = 0u; }
            f32x4 z = {0.f, 0.f, 0.f, 0.f};
            acc[mt] = __builtin_amdgcn_mfma_f32_16x16x32_bf16(a.v, b.v, z, 0, 0, 0);
        }
        // u[s] = num * invx[s]; s = mt*16 + quad*4 + r (in-lane)
        const float4* INVX4 = (const float4*)INVX;
        float thr = 0.999f * QNN[q];        // u > thr  <=>  sim > 0.999
        float iq  = (q < 30) ? IQ[q] : 0.f;
        float g[7][4];
        int cnt = 0;
        #pragma unroll
        for (int mt = 0; mt < 7; ++mt) {
            float4 ix = INVX4[mt * 4 + quad];
            float ixa[4] = {ix.x, ix.y, ix.z, ix.w};
            #pragma unroll
            for (int r = 0; r < 4; ++r) {
                float u = acc[mt][r] * ixa[r];
                if (mt == 6 && (quad * 4 + r) >= 4) u = -1e30f;   // s >= 100
                g[mt][r] = u;
                if (do_oh) cnt += (u > thr) ? 1 : 0;
            }
        }
        // in-lane top5-of-28: 7x sort4 + capped merge tree
        #pragma unroll
        for (int mt = 0; mt < 7; ++mt) sort4d(g[mt][0], g[mt][1], g[mt][2], g[mt][3]);
        float p0[5], p1[5], p2[5], q0[5], q1[5], t[5];
        merge44_5(g[0], g[1], p0);
        merge44_5(g[2], g[3], p1);
        merge44_5(g[4], g[5], p2);
        merge55_5(p0, p1, q0);
        merge54_5(p2, g[6], q1);
        merge55_5(q0, q1, t);
        // butterfly across the 4 quads (lanes xor 16, 32; l15 preserved)
        #pragma unroll
        for (int d = 16; d < 64; d <<= 1) {
            float pp[5];
            pp[0] = __shfl_xor(t[0], d); pp[1] = __shfl_xor(t[1], d);
            pp[2] = __shfl_xor(t[2], d); pp[3] = __shfl_xor(t[3], d);
            pp[4] = __shfl_xor(t[4], d);
            if (do_oh) cnt += __shfl_xor(cnt, d);
            float tn[5];
            merge55_5(t, pp, tn);
            t[0] = tn[0]; t[1] = tn[1]; t[2] = tn[2]; t[3] = tn[3]; t[4] = tn[4];
        }
        if (quad == 0 && q < 30) {
            if (do_oh) {
                FE[q][0] = cnt > 0 ? 1.f : 0.f;
                FE[q][1] = (float)(cnt > 5 ? 5 : cnt) * 0.2f;
            }
            FE[q][fbase]     = t[0] * iq;
            FE[q][fbase + 1] = (t[0] + t[1] + t[2] + t[3] + t[4]) * 0.2f * iq;
        }
    };

    // conv for one mt; A-fragments shared across nt tiles [nt0, nt1];
    // bias enters through the MFMA C operand; stores use truncating bf16
    // (intermediate only — ~1 ulp, damped by cos-norm + 0.1-scale MLP).
    auto conv_mt = [&](const uint* src32, uint* dst32, const uint4* wb,
                       const float* bias, int mt, int nt0, int nt1) {
        const ushort* srcU = (const ushort*)src32;
        ushort* dstU = (ushort*)dst32;
        int sa = mt * 16 + l15;
        Frag a[3];
        #pragma unroll
        for (int k = 0; k < 3; ++k) {
            if (sa < 100) {
                int base = 16 + (sa - 1) * 15 + k * 16 + quad * 4;
                a[k].u[0] = src32[base];     a[k].u[1] = src32[base + 1];
                a[k].u[2] = src32[base + 2]; a[k].u[3] = src32[base + 3];
            } else { a[k].u[0] = a[k].u[1] = a[k].u[2] = a[k].u[3] = 0u; }
        }
        for (int nt = nt0; nt <= nt1; ++nt) {
            int o = nt * 16 + l15;
            float bo = bias[o];                        // 0 for o >= 30
            f32x4 acc = {bo, bo, bo, bo};
            #pragma unroll
            for (int k = 0; k < 3; ++k) {
                Frag b;
                b.u4 = wb[o * 12 + k * 4 + quad];
                acc = __builtin_amdgcn_mfma_f32_16x16x32_bf16(a[k].v, b.v, acc, 0, 0, 0);
            }
            if (o < 30) {
                #pragma unroll
                for (int r = 0; r < 4; ++r) {
                    int s = mt * 16 + quad * 4 + r;
                    if (s < 100) {
                        float v = acc[r];
                        v = v >= 0.f ? v : SLOPE * v;
                        v += bf2f(srcU[32 + s * 30 + o]);
                        dstU[32 + s * 30 + o] = f2bf_tr(v);
                    }
                }
            }
        }
    };

    // ---- B2: sim_insens + pool then conv1 XA->XB ----
    sim_pool(qeA, IQI, 2, true);
    conv_mt(XA32, XB32, wb1, BI1, wid,     0, 1);
    conv_mt(XA32, XB32, wb1, BI1, wid + 2, 0, 1);
    conv_mt(XA32, XB32, wb1, BI1, wid + 4, 0, 1);
    conv_mt(XA32, XB32, wb1, BI1, 6,       wid, wid);
    __syncthreads();

    // ---- B3: conv2 XB->XA ----
    conv_mt(XB32, XA32, wb2, BI2, wid,     0, 1);
    conv_mt(XB32, XA32, wb2, BI2, wid + 2, 0, 1);
    conv_mt(XB32, XA32, wb2, BI2, wid + 4, 0, 1);
    conv_mt(XB32, XA32, wb2, BI2, 6,       wid, wid);
    __syncthreads();

    // ---- B4: inverse row norms of conv_res ----
    norms(XA32);
    __syncthreads();

    // ---- B5: sim_sens + pool ----
    sim_pool(qcA, IQS, 4, false);
    __syncthreads();

    // ---- B6: wave0: per-q MLP, butterfly-sum, score write ----
    if (wid == 0) {
        float val = 0.f;
        if (lane < 30) {
            float lo = ws[OFF_LQ2B];
            #pragma unroll
            for (int j = 0; j < 8; ++j) {
                float h = ws[OFF_LQ1B + j];
                #pragma unroll
                for (int f = 0; f < 6; ++f) h += FE[lane][f] * ws[OFF_LQ1W + j*6 + f];
                h = h >= 0.f ? h : SLOPE * h;
                lo += h * ws[OFF_LQ2W + j];
            }
            val = lo * ws[OFF_QW + lane];
        }
        for (int d = 32; d >= 1; d >>= 1) val += __shfl_xor(val, d);
        if (lane == 0) {
            float emit = val * (1.f / 30.f);
            float z = ws[OFF_SOB];
            z += ga0 * ws[OFF_SOW + 0];
            z += ga1 * ws[OFF_SOW + 1];
            z += ga2 * ws[OFF_SOW + 2];
            z += emit * ws[OFF_SOW + 3];
            float sc = 1.f / (1.f + expf(-z));
            if (bf) ((__hip_bfloat16*)out)[1 + n] = __float2bfloat16(sc);
            else    ((float*)out)[1 + n] = sc;
        }
    }
}

// ---------------- kernel 3: doc-level head ----------------
__global__ __launch_bounds__(256) void k_final(const void* docgaf_in, void* out, const float* ws) {
    const int tid = threadIdx.x;
    const int bf = ((const int*)ws)[0];
    __shared__ float red[256];
    float m = -1e30f;
    for (int i = tid; i < 4000; i += 256) {
        float v = bf ? __bfloat162float(((const __hip_bfloat16*)out)[1 + i])
                     : ((const float*)out)[1 + i];
        m = fmaxf(m, v);
    }
    red[tid] = m;
    __syncthreads();
    for (int off = 128; off > 0; off >>= 1) {
        if (tid < off) red[tid] = fmaxf(red[tid], red[tid + off]);
        __syncthreads();
    }
    if (tid == 0) {
        float f = ws[OFF_FLB] + red[0] * ws[OFF_FLW + 0];
        for (int i = 0; i < 4; ++i) f += ldx(docgaf_in, i, bf) * ws[OFF_FLW + 1 + i];
        if (bf) ((__hip_bfloat16*)out)[0] = __float2bfloat16(f);
        else    ((float*)out)[0] = f;
    }
}

extern "C" void kernel_launch(void* const* d_in, const int* in_sizes, int n_in,
                              void* d_out, int out_size, void* d_ws, size_t ws_size,
                              hipStream_t stream) {
    float* ws = (float*)d_ws;
    k_prep<<<3, 256, 0, stream>>>(d_in[0], d_in[2], d_in[3], d_in[5], d_in[6], d_in[7], d_in[8],
                                  d_in[9], d_in[10], d_in[11], d_in[12], d_in[13], d_in[14],
                                  d_in[15], d_in[16], d_in[17], d_in[18], ws);
    k_main<<<4000, 128, 0, stream>>>(d_in[0], d_in[1], d_out, ws);
    k_final<<<1, 256, 0, stream>>>(d_in[4], d_out, ws);
}